// Round 8
// baseline (155.126 us; speedup 1.0000x reference)
//
#include <hip/hip_runtime.h>
#include <hip/hip_bf16.h>

#define NODE 1024
#define BS 8
#define NBLK 256

struct alignas(8) bf4 { __hip_bfloat16 a, b, c, d; };
typedef short short8 __attribute__((ext_vector_type(8)));
typedef float f32x16 __attribute__((ext_vector_type(16)));

__device__ __forceinline__ short bf16bits(float f) {
    __hip_bfloat16 h = __float2bfloat16(f);
    return *reinterpret_cast<short*>(&h);
}

// ===========================================================================
// FRAGMENT LAYOUTS (mfma_f32_32x32x16_bf16, lane = l31 + 32*hi):
//   A_lds tile (nloc,m): ((m>>4)*2 + ((m>>3)&1))*256 + nloc*8 + (m&7)   [elems]
//   xTf (b,f,m):  (((b*2+(f>>5))*64 + (m>>4))*2 + ((m>>3)&1))*256 + (f&31)*8 + (m&7)
//   xgf (row,k):  ((row>>5)*13 + (k>>4))*512 + ((k>>3)&1)*256 + (row&31)*8 + (k&7)
//   wtf (d,o,k):  (((d*2+(o>>5))*13 + (k>>4))*2 + ((k>>3)&1))*256 + (o&31)*8 + (k&7)
// One persistent kernel; block = (b, 32-node tile); A-tile lives in LDS only.
// ===========================================================================

__device__ __forceinline__ void gridbar(unsigned* c) {
    __syncthreads();
    if (threadIdx.x == 0) {
        __threadfence();   // agent-scope release: flush our XCD L2
        __hip_atomic_fetch_add(c, 1u, __ATOMIC_ACQ_REL, __HIP_MEMORY_SCOPE_AGENT);
        while (__hip_atomic_load(c, __ATOMIC_ACQUIRE, __HIP_MEMORY_SCOPE_AGENT) < NBLK)
            __builtin_amdgcn_s_sleep(2);
    }
    __syncthreads();
}

template<bool FIRST>
__device__ __forceinline__ void spmm_phase(const __hip_bfloat16* A_lds,
                                           float (*P)[2][32][33],
                                           const __hip_bfloat16* __restrict__ srcTf,
                                           const float* __restrict__ xres,
                                           __hip_bfloat16* __restrict__ xgf,
                                           __hip_bfloat16* __restrict__ y1Tf,
                                           int b, int ntile, int w, int l31, int hi) {
    int fh = w & 1, kq = w >> 1;      // feature half x K quarter (8 waves)
    const __hip_bfloat16* pa = srcTf + (((size_t)(b * 2 + fh) * 64 + kq * 16) * 2 + hi) * 256 + l31 * 8;
    const __hip_bfloat16* pb = A_lds + ((size_t)(kq * 16) * 2 + hi) * 256 + l31 * 8;

    f32x16 a0, a1;
#pragma unroll
    for (int i = 0; i < 16; ++i) { a0[i] = 0.f; a1[i] = 0.f; }
#pragma unroll
    for (int gi = 0; gi < 16; gi += 2) {
        short8 av0 = *(const short8*)(pa + (size_t)gi * 512);
        short8 bv0 = *(const short8*)(pb + (size_t)gi * 512);
        short8 av1 = *(const short8*)(pa + (size_t)gi * 512 + 512);
        short8 bv1 = *(const short8*)(pb + (size_t)gi * 512 + 512);
        a0 = __builtin_amdgcn_mfma_f32_32x32x16_bf16(av0, bv0, a0, 0, 0, 0);
        a1 = __builtin_amdgcn_mfma_f32_32x32x16_bf16(av1, bv1, a1, 0, 0, 0);
    }
#pragma unroll
    for (int i = 0; i < 16; ++i) a0[i] += a1[i];

    if (kq != 0) {
#pragma unroll
        for (int r = 0; r < 16; ++r)
            P[kq - 1][fh][l31][hi * 4 + (r >> 2) * 8 + (r & 3)] = a0[r];
    }
    __syncthreads();
    if (kq == 0) {
#pragma unroll
        for (int r = 0; r < 16; ++r) {
            int f = hi * 4 + (r >> 2) * 8 + (r & 3);
            a0[r] += P[0][fh][l31][f] + P[1][fh][l31][f] + P[2][fh][l31][f];
        }
        size_t rtg = (size_t)b * 32 + ntile;
        int node = ntile * 32 + l31;
        size_t row = (size_t)b * 1024 + node;
#pragma unroll
        for (int rg = 0; rg < 4; ++rg) {
            int fb = fh * 32 + hi * 4 + rg * 8;
            float vx = a0[rg * 4], vy = a0[rg * 4 + 1];
            float vz = a0[rg * 4 + 2], vw = a0[rg * 4 + 3];
            if (!FIRST) {
                float4 xv = *(const float4*)(xres + row * 64 + fb);
                vx = 2.f * vx - xv.x; vy = 2.f * vy - xv.y;
                vz = 2.f * vz - xv.z; vw = 2.f * vw - xv.w;
            }
            bf4 o;
            o.a = __float2bfloat16(vx); o.b = __float2bfloat16(vy);
            o.c = __float2bfloat16(vz); o.d = __float2bfloat16(vw);
            int kstep = (FIRST ? 4 : 8) + fh * 2 + (rg >> 1);
            *(bf4*)(xgf + (rtg * 13 + kstep) * 512 + (rg & 1) * 256 + l31 * 8 + hi * 4) = o;
        }
        if (FIRST) {
#pragma unroll
            for (int r = 0; r < 16; ++r) {
                int f = fh * 32 + hi * 4 + (r >> 2) * 8 + (r & 3);
                size_t addr = (((size_t)(b * 2 + fh) * 64 + (node >> 4)) * 2 + ((l31 >> 3) & 1)) * 256
                              + (f & 31) * 8 + (l31 & 7);
                y1Tf[addr] = __float2bfloat16(a0[r]);
            }
        }
    }
}

__global__ __launch_bounds__(512) void k_all(const float* __restrict__ x,
                                             const float* __restrict__ ne,
                                             const float* __restrict__ t,
                                             const float* __restrict__ nt,
                                             const float* __restrict__ W,
                                             const float* __restrict__ bp,
                                             __hip_bfloat16* __restrict__ xTf,
                                             __hip_bfloat16* __restrict__ y1Tf,
                                             __hip_bfloat16* __restrict__ xgf,
                                             __hip_bfloat16* __restrict__ wtf,
                                             unsigned* __restrict__ bar,
                                             float* __restrict__ out) {
    // LDS overlays (133KB total -> 1 block/CU -> all 256 blocks resident):
    //  bufA: [A_lds 64K | nel 45K] phases 0-2 ; PF[8][32][67] (68.6K) phase 3
    //  bufB: T[64][72] (9.2K) phase 0 ; P[3][2][32][33] (25.3K) phases 1-2
    __shared__ __align__(16) char bufA[110592];
    __shared__ __align__(16) char bufB[25344];
    __hip_bfloat16* A_lds = (__hip_bfloat16*)bufA;
    float* nel = (float*)(bufA + 65536);
    typedef __hip_bfloat16 row72[72];
    row72* T = (row72*)bufB;
    typedef float p_t[2][32][33];
    p_t* P = (p_t*)bufB;
    typedef float pf_t[32][67];
    pf_t* PF = (pf_t*)bufA;

    int bidx = blockIdx.x;
    int tid = threadIdx.x;
    int w = tid >> 6, lane = tid & 63;
    int l31 = lane & 31, hi = lane >> 5;
    int b = bidx >> 5, ntile = bidx & 31;

    // ---------------- phase 0: attn dots + prep ----------------
    for (int i = tid; i < NODE * 10; i += 512) nel[(i / 10) * 11 + (i % 10)] = ne[i];
    float at = 0.f;
#pragma unroll
    for (int j = 0; j < 6; ++j) at += nt[b * 6 + j] * t[b * 6 + j];
    __syncthreads();

    // dots: wave w owns rows w*4..w*4+3; lane owns m = lane + 64j (conflict-free)
    float nr[4][10];
#pragma unroll
    for (int rr = 0; rr < 4; ++rr) {
        int n = ntile * 32 + w * 4 + rr;
#pragma unroll
        for (int d = 0; d < 10; ++d) nr[rr][d] = nel[n * 11 + d];
    }
    float z[4][16];
#pragma unroll
    for (int j = 0; j < 16; ++j) {
        int m = lane + (j << 6);
        float mr[10];
#pragma unroll
        for (int d = 0; d < 10; ++d) mr[d] = nel[m * 11 + d];
#pragma unroll
        for (int rr = 0; rr < 4; ++rr) {
            float s = 0.f;
#pragma unroll
            for (int d = 0; d < 10; ++d) s += nr[rr][d] * mr[d];
            z[rr][j] = s;
        }
    }

    // prep work (concurrent, independent outputs)
    if (bidx < 128) {
        int pb = bidx >> 4, pn0 = (bidx & 15) * 64;
        {
            int i = tid;
            int il = i & 31, ih = (i >> 5) & 1, iks = (i >> 6) & 3, irt = i >> 8;
            int node = pn0 + irt * 32 + il;
            const float* src = x + ((size_t)pb * 1024 + node) * 64 + iks * 16 + ih * 8;
            short8 o;
#pragma unroll
            for (int j = 0; j < 8; ++j) o[j] = bf16bits(src[j]);
            size_t rtg = (size_t)pb * 32 + (pn0 >> 5) + irt;
            *(short8*)(xgf + (rtg * 13 + iks) * 512 + ih * 256 + il * 8) = o;
#pragma unroll
            for (int j = 0; j < 8; ++j) {
                __hip_bfloat16 h;
                *reinterpret_cast<short*>(&h) = o[j];
                T[iks * 16 + ih * 8 + j][irt * 32 + il] = h;
            }
        }
        for (int q = tid; q < 1024; q += 512) {   // bias window kstep 12
            int qrt = q >> 9, e = q & 511;
            size_t rtg = (size_t)pb * 32 + (pn0 >> 5) + qrt;
            xgf[(rtg * 13 + 12) * 512 + e] = __float2bfloat16(((e & 7) == 0 && e < 256) ? 1.0f : 0.0f);
        }
    } else if (bidx < 144) {
        int d = bidx - 128;
        const float* Wd = W + (size_t)d * 192 * 64;
        for (int i = tid; i < 1664; i += 512) {
            int il = i & 31, ih = (i >> 5) & 1;
            int ks = (i >> 6) % 13, oh = (i >> 6) / 13;
            int o = oh * 32 + il;
            short8 v;
#pragma unroll
            for (int j = 0; j < 8; ++j) {
                int k = ks * 16 + ih * 8 + j;
                float f = (k < 192) ? Wd[(size_t)k * 64 + o]
                                    : ((k == 192) ? bp[d * 64 + o] : 0.0f);
                v[j] = bf16bits(f);
            }
            *(short8*)(wtf + ((((size_t)d * 2 + oh) * 13 + ks) * 2 + ih) * 256 + il * 8) = v;
        }
    }
    __syncthreads();   // T ready; nel reads done

    // softmax (no max-subtract: logits << 88) + write A-tile into LDS frags
#pragma unroll
    for (int rr = 0; rr < 4; ++rr) {
        float s = 0.f;
#pragma unroll
        for (int j = 0; j < 16; ++j) {
            float u = __expf(fmaxf(z[rr][j] + at, 0.f));
            z[rr][j] = u;
            s += u;
        }
#pragma unroll
        for (int off = 32; off > 0; off >>= 1) s += __shfl_xor(s, off);
        float inv = 1.f / s;
        int nloc = w * 4 + rr;
#pragma unroll
        for (int j = 0; j < 16; ++j) {
            int idx = (((lane >> 4) + 4 * j) * 2 + ((lane >> 3) & 1)) * 256 + nloc * 8 + (lane & 7);
            A_lds[idx] = __float2bfloat16(z[rr][j] * inv);
        }
    }
    if (bidx < 128) {   // prep part B: xTf frags from T
        int pb = bidx >> 4, pn0 = (bidx & 15) * 64;
        int fh2 = tid >> 8, inner = tid & 255;
        int f = fh2 * 32 + (inner & 31), m8 = inner >> 5;
        int m = pn0 + m8 * 8;
        short8 o;
#pragma unroll
        for (int j = 0; j < 8; ++j) {
            __hip_bfloat16 h = T[f][m8 * 8 + j];
            o[j] = *reinterpret_cast<short*>(&h);
        }
        *(short8*)(xTf + (((size_t)(pb * 2 + fh2) * 64 + (m >> 4)) * 2 + ((m >> 3) & 1)) * 256 + (f & 31) * 8) = o;
    }

    gridbar(&bar[0]);   // xTf, wtf, xgf(k0-3,12) visible device-wide

    // ---------------- phase 1: y1 = A @ x ----------------
    spmm_phase<true>(A_lds, P, xTf, x, xgf, y1Tf, b, ntile, w, l31, hi);

    gridbar(&bar[1]);   // y1Tf visible device-wide

    // ---------------- phase 2: y2 = 2 A y1 - x ----------------
    spmm_phase<false>(A_lds, P, y1Tf, x, xgf, y1Tf, b, ntile, w, l31, hi);

    __syncthreads();    // xgf(k8-11) visible block-locally; A_lds dead -> PF may reuse

    // ---------------- phase 3: fuse -> out ----------------
    {
        int rt = bidx;
        int m0 = rt * 32;
        int n = ntile * 32 + l31;
        int d0 = 2 * w, d1 = 2 * w + 1;
        float e0 = (d0 < 10) ? ne[n * 10 + d0] : nt[b * 6 + (d0 - 10)];
        float e1 = (d1 < 10) ? ne[n * 10 + d1] : nt[b * 6 + (d1 - 10)];

        short8 xf[13];
        const __hip_bfloat16* px = xgf + (size_t)rt * 6656 + hi * 256 + l31 * 8;
#pragma unroll
        for (int k = 0; k < 13; ++k) xf[k] = *(const short8*)(px + k * 512);

        f32x16 z00, z01, z10, z11;
#pragma unroll
        for (int i = 0; i < 16; ++i) { z00[i] = 0.f; z01[i] = 0.f; z10[i] = 0.f; z11[i] = 0.f; }

        const __hip_bfloat16* pw0 = wtf + (size_t)d0 * 13312 + hi * 256 + l31 * 8;
#pragma unroll
        for (int k = 0; k < 13; ++k) {
            short8 a00 = *(const short8*)(pw0 + k * 512);
            short8 a01 = *(const short8*)(pw0 + 6656 + k * 512);
            short8 a10 = *(const short8*)(pw0 + 13312 + k * 512);
            short8 a11 = *(const short8*)(pw0 + 13312 + 6656 + k * 512);
            z00 = __builtin_amdgcn_mfma_f32_32x32x16_bf16(a00, xf[k], z00, 0, 0, 0);
            z01 = __builtin_amdgcn_mfma_f32_32x32x16_bf16(a01, xf[k], z01, 0, 0, 0);
            z10 = __builtin_amdgcn_mfma_f32_32x32x16_bf16(a10, xf[k], z10, 0, 0, 0);
            z11 = __builtin_amdgcn_mfma_f32_32x32x16_bf16(a11, xf[k], z11, 0, 0, 0);
        }
#pragma unroll
        for (int r = 0; r < 16; ++r) {
            int o = (r & 3) + 8 * (r >> 2) + 4 * hi;
            PF[w][l31][o]      = e0 * z00[r] + e1 * z10[r];
            PF[w][l31][o + 32] = e0 * z01[r] + e1 * z11[r];
        }
        __syncthreads();

        int m = tid >> 4, o0 = (tid & 15) * 4;
        float s0 = 0.f, s1 = 0.f, s2 = 0.f, s3 = 0.f;
#pragma unroll
        for (int ww = 0; ww < 8; ++ww) {
            s0 += PF[ww][m][o0];
            s1 += PF[ww][m][o0 + 1];
            s2 += PF[ww][m][o0 + 2];
            s3 += PF[ww][m][o0 + 3];
        }
        *(float4*)(out + (size_t)(m0 + m) * 64 + o0) = make_float4(s0, s1, s2, s3);
    }
}

// ---------------------------------------------------------------------------
extern "C" void kernel_launch(void* const* d_in, const int* in_sizes, int n_in,
                              void* d_out, int out_size, void* d_ws, size_t ws_size,
                              hipStream_t stream) {
    const float* x  = (const float*)d_in[0];   // [8,1024,64]
    const float* ne = (const float*)d_in[1];   // [1024,10]
    const float* t  = (const float*)d_in[2];   // [8,6]
    const float* nt = (const float*)d_in[3];   // [8,6]
    const float* W  = (const float*)d_in[5];   // [16,3,64,64]
    const float* bp = (const float*)d_in[6];   // [16,64]
    float* out = (float*)d_out;                // [8,1024,64]

    __hip_bfloat16* wsb = (__hip_bfloat16*)d_ws;
    __hip_bfloat16* xTf  = wsb;                  //   524,288 elems
    __hip_bfloat16* y1Tf = wsb + 524288;         //   524,288
    __hip_bfloat16* xgf  = wsb + 1048576;        // 1,703,936
    __hip_bfloat16* wtf  = wsb + 2752512;        //   212,992
    unsigned* bar = (unsigned*)((char*)d_ws + (8u << 20));   // 2 counters, zeroed below

    hipMemsetAsync(bar, 0, 64, stream);
    k_all<<<NBLK, 512, 0, stream>>>(x, ne, t, nt, W, bp, xTf, y1Tf, xgf, wtf, bar, out);
}

// Round 10
// 121.501 us; speedup vs baseline: 1.2767x; 1.2767x over previous
//
#include <hip/hip_runtime.h>
#include <hip/hip_bf16.h>

#define NODE 1024
#define BS 8
#define XG_K 208   // 192 ki + 1 bias + 15 zero-pad (13 K-windows of 16)

struct alignas(8) bf4 { __hip_bfloat16 a, b, c, d; };
typedef short short8 __attribute__((ext_vector_type(8)));
typedef float f32x16 __attribute__((ext_vector_type(16)));

__device__ __forceinline__ short bf16bits(float f) {
    __hip_bfloat16 h = __float2bfloat16(f);
    return *reinterpret_cast<short*>(&h);
}

// ---------------------------------------------------------------------------
// K1 (4-way merged, 416 blocks x 256):
//   0..255  : attn v3 — wave-per-row a=ne@neT, 8x relu-softmax -> A16 (row-major)
//   256..383: x -> xT bf16 + xg rows k0..63 + bias window k192..207
//   384..399: W,bp -> wt[d][o][208] row-major bf16
//   400..415: Wb[b][o][208] = sum_{dd<6} nt[b,dd]*Wt[10+dd]  (folds nt-part + its bias)
// ---------------------------------------------------------------------------
__global__ __launch_bounds__(256) void k_front(const float* __restrict__ ne,
                                               const float* __restrict__ t,
                                               const float* __restrict__ nt,
                                               const float* __restrict__ x,
                                               const float* __restrict__ W,
                                               const float* __restrict__ bp,
                                               __hip_bfloat16* __restrict__ A16,
                                               __hip_bfloat16* __restrict__ xT,
                                               __hip_bfloat16* __restrict__ xg,
                                               __hip_bfloat16* __restrict__ wt,
                                               __hip_bfloat16* __restrict__ wb) {
    __shared__ __align__(16) char shbuf[45056];
    int bidx = blockIdx.x;
    int tid = threadIdx.x;

    if (bidx < 256) {
        // ---------------- attn v3 (R6-proven) ----------------
        float* nel = (float*)shbuf;
        int w = tid >> 6, lane = tid & 63;
        int n = (bidx << 2) + w;

        for (int i = tid; i < NODE * 10; i += 256) nel[(i / 10) * 11 + (i % 10)] = ne[i];

        float at[8];
#pragma unroll
        for (int b = 0; b < 8; ++b) {
            float s = 0.f;
#pragma unroll
            for (int j = 0; j < 6; ++j) s += nt[b * 6 + j] * t[b * 6 + j];
            at[b] = s;
        }
        __syncthreads();

        float nr[10];
#pragma unroll
        for (int d = 0; d < 10; ++d) nr[d] = nel[n * 11 + d];

        float v[16];
#pragma unroll
        for (int j = 0; j < 16; ++j) {
            const float* row = &nel[(lane + (j << 6)) * 11];
            float s = 0.f;
#pragma unroll
            for (int d = 0; d < 10; ++d) s += nr[d] * row[d];
            v[j] = s;
        }

#pragma unroll
        for (int b = 0; b < 8; ++b) {
            float u[16], s = 0.f;
#pragma unroll
            for (int j = 0; j < 16; ++j) {
                u[j] = __expf(fmaxf(v[j] + at[b], 0.f));
                s += u[j];
            }
#pragma unroll
            for (int off = 32; off > 0; off >>= 1) s += __shfl_xor(s, off);
            float inv = 1.f / s;
            __hip_bfloat16* dst = A16 + (((size_t)(b << 10) + n) << 10);
#pragma unroll
            for (int j = 0; j < 16; ++j) dst[lane + (j << 6)] = __float2bfloat16(u[j] * inv);
        }
    } else if (bidx < 384) {
        // ---------------- prep x ----------------
        typedef __hip_bfloat16 row72[72];
        row72* T = (row72*)shbuf;
        int bx = bidx - 256;
        int b = bx >> 4;
        int n0 = (bx & 15) * 64;
        int nloc = tid >> 2, f0 = (tid & 3) * 16;
        size_t row = (size_t)(b << 10) + n0 + nloc;
        {
            const float* src = x + row * 64 + f0;
            __hip_bfloat16* dst = xg + row * XG_K + f0;
#pragma unroll
            for (int j = 0; j < 16; j += 4) {
                float4 vv = *(const float4*)(src + j);
                bf4 o;
                o.a = __float2bfloat16(vv.x); o.b = __float2bfloat16(vv.y);
                o.c = __float2bfloat16(vv.z); o.d = __float2bfloat16(vv.w);
                *(bf4*)(dst + j) = o;
                T[f0 + j][nloc] = o.a; T[f0 + j + 1][nloc] = o.b;
                T[f0 + j + 2][nloc] = o.c; T[f0 + j + 3][nloc] = o.d;
            }
        }
        if (tid < 64) {
            __hip_bfloat16* d2 = xg + ((size_t)(b << 10) + n0 + tid) * XG_K + 192;
            d2[0] = __float2bfloat16(1.0f);
#pragma unroll
            for (int j = 1; j < 16; ++j) d2[j] = __float2bfloat16(0.0f);
        }
        __syncthreads();
        {
            int f = tid >> 2, c0 = (tid & 3) * 16;
            __hip_bfloat16* dst = xT + ((size_t)b * 64 + f) * 1024 + n0 + c0;
#pragma unroll
            for (int j = 0; j < 16; ++j) dst[j] = T[f][c0 + j];
        }
    } else if (bidx < 400) {
        // ---------------- prep wt ----------------
        int d = bidx - 384;
        const float* Wd = W + (size_t)d * 192 * 64;
        __hip_bfloat16* dst = wt + (size_t)d * 64 * XG_K;
        for (int i = tid; i < 64 * XG_K; i += 256) {
            int o = i / XG_K, k = i % XG_K;
            float f = (k < 192) ? Wd[(size_t)k * 64 + o]
                                : ((k == 192) ? bp[d * 64 + o] : 0.0f);
            dst[i] = __float2bfloat16(f);
        }
    } else {
        // ---------------- prep Wb ----------------
        int idx = bidx - 400;
        int b = idx >> 1, oh = idx & 1;
        float ntl[6];
#pragma unroll
        for (int dd = 0; dd < 6; ++dd) ntl[dd] = nt[b * 6 + dd];
        __hip_bfloat16* dst = wb + (size_t)b * 64 * XG_K + oh * 32 * XG_K;
        for (int i = tid; i < 32 * XG_K; i += 256) {
            int ol = i / XG_K, k = i % XG_K;
            int o = oh * 32 + ol;
            float s = 0.f;
            if (k < 192) {
#pragma unroll
                for (int dd = 0; dd < 6; ++dd)
                    s += ntl[dd] * W[((size_t)(10 + dd) * 192 + k) * 64 + o];
            } else if (k == 192) {
#pragma unroll
                for (int dd = 0; dd < 6; ++dd)
                    s += ntl[dd] * bp[(10 + dd) * 64 + o];
            }
            dst[i] = __float2bfloat16(s);
        }
    }
}

// ---------------------------------------------------------------------------
// K2: spmm1 (R6-proven). y1 = A @ x. 4 waves (fh, kh); split-K via LDS.
// writes xg k-windows 4..7 (row-major) + y1T [b][f][node] row-major.
// ---------------------------------------------------------------------------
#define LOADG(slot, g) do {                                                   \
    const __hip_bfloat16* qa = pa + (g) * 64;                                 \
    const __hip_bfloat16* qb = pb + (g) * 64;                                 \
    as[slot][0] = *(const short8*)(qa);      as[slot][1] = *(const short8*)(qa + 16); \
    as[slot][2] = *(const short8*)(qa + 32); as[slot][3] = *(const short8*)(qa + 48); \
    bs[slot][0] = *(const short8*)(qb);      bs[slot][1] = *(const short8*)(qb + 16); \
    bs[slot][2] = *(const short8*)(qb + 32); bs[slot][3] = *(const short8*)(qb + 48); \
} while (0)

__global__ __launch_bounds__(256) void k_spmm1(const __hip_bfloat16* __restrict__ A16,
                                               const __hip_bfloat16* __restrict__ xT,
                                               __hip_bfloat16* __restrict__ xg,
                                               __hip_bfloat16* __restrict__ y1T) {
    __shared__ float P[2][32][67];
    int b = blockIdx.x >> 5;
    int n0 = (blockIdx.x & 31) << 5;
    int tid = threadIdx.x;
    int wv = tid >> 6, lane = tid & 63;
    int fh = wv & 1, kh = wv >> 1;
    int l31 = lane & 31, hi = lane >> 5;

    const __hip_bfloat16* pa = xT + ((size_t)b * 64 + fh * 32 + l31) * 1024 + (kh << 9) + hi * 8;
    const __hip_bfloat16* pb = A16 + ((size_t)b << 20) + (size_t)(n0 + l31) * 1024 + (kh << 9) + hi * 8;

    f32x16 acc0, acc1;
#pragma unroll
    for (int i = 0; i < 16; ++i) { acc0[i] = 0.f; acc1[i] = 0.f; }

    short8 as[3][4], bs[3][4];
    LOADG(0, 0);
    LOADG(1, 1);
#pragma unroll
    for (int g = 0; g < 8; ++g) {
        if (g + 2 < 8) { LOADG((g + 2) % 3, g + 2); }
        int cu = g % 3;
        acc0 = __builtin_amdgcn_mfma_f32_32x32x16_bf16(as[cu][0], bs[cu][0], acc0, 0, 0, 0);
        acc1 = __builtin_amdgcn_mfma_f32_32x32x16_bf16(as[cu][1], bs[cu][1], acc1, 0, 0, 0);
        acc0 = __builtin_amdgcn_mfma_f32_32x32x16_bf16(as[cu][2], bs[cu][2], acc0, 0, 0, 0);
        acc1 = __builtin_amdgcn_mfma_f32_32x32x16_bf16(as[cu][3], bs[cu][3], acc1, 0, 0, 0);
    }
#pragma unroll
    for (int i = 0; i < 16; ++i) acc0[i] += acc1[i];

    if (kh == 1) {
#pragma unroll
        for (int r = 0; r < 16; ++r)
            P[fh][l31][hi * 4 + (r >> 2) * 8 + (r & 3)] = acc0[r];
    }
    __syncthreads();
    if (kh == 0) {
#pragma unroll
        for (int r = 0; r < 16; ++r)
            acc0[r] += P[fh][l31][hi * 4 + (r >> 2) * 8 + (r & 3)];

        int node = n0 + l31;
        size_t row = (size_t)(b << 10) + node;
#pragma unroll
        for (int rg = 0; rg < 4; ++rg) {
            int fb = fh * 32 + hi * 4 + rg * 8;
            bf4 o;
            o.a = __float2bfloat16(acc0[rg * 4]);
            o.b = __float2bfloat16(acc0[rg * 4 + 1]);
            o.c = __float2bfloat16(acc0[rg * 4 + 2]);
            o.d = __float2bfloat16(acc0[rg * 4 + 3]);
            *(bf4*)(xg + row * XG_K + 64 + fb) = o;
        }
#pragma unroll
        for (int r = 0; r < 16; ++r) {
            int f = fh * 32 + hi * 4 + (r >> 2) * 8 + (r & 3);
            y1T[((size_t)b * 64 + f) * 1024 + node] = __float2bfloat16(acc0[r]);
        }
    }
}

// ---------------------------------------------------------------------------
// K3: spmm2 + fuse, block-local handoff. 256 blocks x 512 (8 waves).
// Phase A: y2 = 2*A@y1 - x for this tile (8-wave 4-way split-K) -> LDS Y2.
// Phase B: out = sum_s e_s * (Ws . xg)  with s = {10 ne-dims, Wb, zero};
//          xg k8..11 read from Y2 (LDS), rest from global. 6 working waves.
// ---------------------------------------------------------------------------
__global__ __launch_bounds__(512) void k_sf(const __hip_bfloat16* __restrict__ A16,
                                            const __hip_bfloat16* __restrict__ y1T,
                                            const float* __restrict__ x,
                                            const __hip_bfloat16* __restrict__ xg,
                                            const __hip_bfloat16* __restrict__ wt,
                                            const __hip_bfloat16* __restrict__ wb,
                                            const float* __restrict__ ne,
                                            float* __restrict__ out) {
    __shared__ __align__(16) char buf[51456];        // P (25.3K) then PF (51.5K)
    __shared__ __hip_bfloat16 Y2[32][66];
    typedef float p3_t[2][32][33];
    p3_t* P = (p3_t*)buf;                            // [3][2][32][33]
    typedef float pf_t[32][67];
    pf_t* PF = (pf_t*)buf;                           // [6][32][67]

    int bidx = blockIdx.x;
    int b = bidx >> 5, ntile = bidx & 31;
    int n0 = ntile << 5;
    int tid = threadIdx.x;
    int w = tid >> 6, lane = tid & 63;
    int l31 = lane & 31, hi = lane >> 5;

    // ---------------- phase A: spmm2 ----------------
    {
        int fh = w & 1, kq = w >> 1;
        const __hip_bfloat16* pa = y1T + ((size_t)b * 64 + fh * 32 + l31) * 1024 + kq * 256 + hi * 8;
        const __hip_bfloat16* pb = A16 + ((size_t)b << 20) + (size_t)(n0 + l31) * 1024 + kq * 256 + hi * 8;

        f32x16 a0, a1;
#pragma unroll
        for (int i = 0; i < 16; ++i) { a0[i] = 0.f; a1[i] = 0.f; }
#pragma unroll
        for (int gi = 0; gi < 16; gi += 2) {
            short8 av0 = *(const short8*)(pa + gi * 16);
            short8 bv0 = *(const short8*)(pb + gi * 16);
            short8 av1 = *(const short8*)(pa + gi * 16 + 16);
            short8 bv1 = *(const short8*)(pb + gi * 16 + 16);
            a0 = __builtin_amdgcn_mfma_f32_32x32x16_bf16(av0, bv0, a0, 0, 0, 0);
            a1 = __builtin_amdgcn_mfma_f32_32x32x16_bf16(av1, bv1, a1, 0, 0, 0);
        }
#pragma unroll
        for (int i = 0; i < 16; ++i) a0[i] += a1[i];

        if (kq != 0) {
#pragma unroll
            for (int r = 0; r < 16; ++r)
                P[kq - 1][fh][l31][hi * 4 + (r >> 2) * 8 + (r & 3)] = a0[r];
        }
        __syncthreads();
        if (kq == 0) {
#pragma unroll
            for (int r = 0; r < 16; ++r) {
                int f = hi * 4 + (r >> 2) * 8 + (r & 3);
                a0[r] += P[0][fh][l31][f] + P[1][fh][l31][f] + P[2][fh][l31][f];
            }
            size_t row = (size_t)(b << 10) + n0 + l31;
#pragma unroll
            for (int rg = 0; rg < 4; ++rg) {
                int fb = fh * 32 + hi * 4 + rg * 8;
                float4 xv = *(const float4*)(x + row * 64 + fb);
                bf4 o;
                o.a = __float2bfloat16(2.f * a0[rg * 4]     - xv.x);
                o.b = __float2bfloat16(2.f * a0[rg * 4 + 1] - xv.y);
                o.c = __float2bfloat16(2.f * a0[rg * 4 + 2] - xv.z);
                o.d = __float2bfloat16(2.f * a0[rg * 4 + 3] - xv.w);
                *(bf4*)(&Y2[l31][fb]) = o;
            }
        }
    }
    __syncthreads();   // Y2 ready; P dead -> PF may reuse buf

    // ---------------- phase B: fuse ----------------
    if (w < 6) {
        int n = n0 + l31;
        int s0 = 2 * w, s1 = 2 * w + 1;
        float e0, e1;
        const __hip_bfloat16 *base0, *base1;
        if (w < 5) {
            e0 = ne[n * 10 + s0];
            e1 = ne[n * 10 + s1];
            base0 = wt + ((size_t)s0 * 64 + l31) * XG_K + hi * 8;
            base1 = wt + ((size_t)s1 * 64 + l31) * XG_K + hi * 8;
        } else {
            e0 = 1.0f;
            e1 = 0.0f;
            base0 = wb + ((size_t)b * 64 + l31) * XG_K + hi * 8;
            base1 = base0;
        }

        short8 xf[13];
        const __hip_bfloat16* px = xg + ((size_t)(bidx * 32) + l31) * XG_K + hi * 8;
#pragma unroll
        for (int wk = 0; wk < 13; ++wk) {
            if (wk >= 8 && wk < 12)
                xf[wk] = *(const short8*)(&Y2[l31][(wk - 8) * 16 + hi * 8]);
            else
                xf[wk] = *(const short8*)(px + wk * 16);
        }

        f32x16 z00, z01, z10, z11;
#pragma unroll
        for (int i = 0; i < 16; ++i) { z00[i] = 0.f; z01[i] = 0.f; z10[i] = 0.f; z11[i] = 0.f; }

#pragma unroll
        for (int wk = 0; wk < 13; ++wk) {
            short8 a00 = *(const short8*)(base0 + wk * 16);
            short8 a01 = *(const short8*)(base0 + (size_t)32 * XG_K + wk * 16);
            short8 a10 = *(const short8*)(base1 + wk * 16);
            short8 a11 = *(const short8*)(base1 + (size_t)32 * XG_K + wk * 16);
            z00 = __builtin_amdgcn_mfma_f32_32x32x16_bf16(a00, xf[wk], z00, 0, 0, 0);
            z01 = __builtin_amdgcn_mfma_f32_32x32x16_bf16(a01, xf[wk], z01, 0, 0, 0);
            z10 = __builtin_amdgcn_mfma_f32_32x32x16_bf16(a10, xf[wk], z10, 0, 0, 0);
            z11 = __builtin_amdgcn_mfma_f32_32x32x16_bf16(a11, xf[wk], z11, 0, 0, 0);
        }
#pragma unroll
        for (int r = 0; r < 16; ++r) {
            int o = (r & 3) + 8 * (r >> 2) + 4 * hi;
            PF[w][l31][o]      = e0 * z00[r] + e1 * z10[r];
            PF[w][l31][o + 32] = e0 * z01[r] + e1 * z11[r];
        }
    }
    __syncthreads();

    int m = tid >> 4, o0 = (tid & 15) * 4;
    float s0 = 0.f, s1 = 0.f, s2 = 0.f, s3 = 0.f;
#pragma unroll
    for (int ww = 0; ww < 6; ++ww) {
        s0 += PF[ww][m][o0];
        s1 += PF[ww][m][o0 + 1];
        s2 += PF[ww][m][o0 + 2];
        s3 += PF[ww][m][o0 + 3];
    }
    *(float4*)(out + ((size_t)(bidx * 32) + m) * 64 + o0) = make_float4(s0, s1, s2, s3);
}

// ---------------------------------------------------------------------------
extern "C" void kernel_launch(void* const* d_in, const int* in_sizes, int n_in,
                              void* d_out, int out_size, void* d_ws, size_t ws_size,
                              hipStream_t stream) {
    const float* x  = (const float*)d_in[0];   // [8,1024,64]
    const float* ne = (const float*)d_in[1];   // [1024,10]
    const float* t  = (const float*)d_in[2];   // [8,6]
    const float* nt = (const float*)d_in[3];   // [8,6]
    const float* W  = (const float*)d_in[5];   // [16,3,64,64]
    const float* bp = (const float*)d_in[6];   // [16,64]
    float* out = (float*)d_out;                // [8,1024,64]

    __hip_bfloat16* wsb = (__hip_bfloat16*)d_ws;
    __hip_bfloat16* A16 = wsb;                       // 8,388,608 elems
    __hip_bfloat16* xT  = wsb + 8388608;             //   524,288
    __hip_bfloat16* y1T = wsb + 8912896;             //   524,288
    __hip_bfloat16* xg  = wsb + 9437184;             // 1,703,936
    __hip_bfloat16* wt  = wsb + 11141120;            //   212,992
    __hip_bfloat16* wb  = wsb + 11354112;            //   106,496

    k_front<<<416, 256, 0, stream>>>(ne, t, nt, x, W, bp, A16, xT, xg, wt, wb);
    k_spmm1<<<BS * 32, 256, 0, stream>>>(A16, xT, xg, y1T);
    k_sf<<<BS * 32, 512, 0, stream>>>(A16, y1T, x, xg, wt, wb, ne, out);
}